// Round 11
// baseline (1147.428 us; speedup 1.0000x reference)
//
#include <hip/hip_runtime.h>
#include <hip/hip_fp16.h>
#include <stdint.h>

typedef float f4 __attribute__((ext_vector_type(4)));

#define BSHIFT 8
#define BMASK  255
#define BCAP   8192   // edges per 256-node bucket (mean 4096 -> 64-sigma headroom)

// ---- device-scope grid barrier (all blocks co-resident by construction) ----
// Arrive: one RMW per block. Poll: plain agent-scope LOAD (no RMW storm / line
// ping-pong — R10's atomicAdd(bar,0) poll was the 1800us disaster).
__device__ __forceinline__ void gridbar(int* bar, int target) {
    __threadfence();                 // release: make this block's writes device-visible
    __syncthreads();
    if (threadIdx.x == 0) {
        atomicAdd(bar, 1);
        while (__hip_atomic_load(bar, __ATOMIC_RELAXED, __HIP_MEMORY_SCOPE_AGENT) < target)
            __builtin_amdgcn_s_sleep(8);
    }
    __syncthreads();
    __threadfence();                 // acquire: drop stale cached lines
}

// ---- gemm phase: g16[row] = fp16(dinv[row] * (src[row] @ W)), 512-B row slots ----
// W fp32 in LDS (64 KB). 1024 thr: r = t>>3 (128 rows/tile), cg = t&7, 16 cols/thread
// at q*32+cg*4 — LDS word offset 4*cg+32q: conflict-free, 8-way same-address broadcast.
// In-place over src safe: a row's 8 threads are in one wave (lockstep).
__device__ __forceinline__ void gemm_phase(f4* wlds, const float* __restrict__ src,
                                           const float* __restrict__ W,
                                           const float* __restrict__ dinv,
                                           __half* __restrict__ g16, int N, int NB) {
    int t = threadIdx.x;
    const f4* w4 = (const f4*)W;
    for (int i = t; i < 4096; i += 1024) wlds[i] = w4[i];
    __syncthreads();
    int r  = t >> 3;           // 0..127
    int cg = t & 7;            // 0..7
    int ntiles = (N + 127) >> 7;
    for (int tile = blockIdx.x; tile < ntiles; tile += NB) {
        int rw  = tile * 128 + r;
        int rwC = rw < N ? rw : N - 1;
        const f4* x4 = (const f4*)(src + (size_t)rwC * 128);
        float dv = dinv[rwC];
        f4 acc[4];
#pragma unroll
        for (int q = 0; q < 4; ++q) acc[q] = (f4)0.0f;
        for (int k4 = 0; k4 < 32; ++k4) {
            f4 xv = x4[k4];
#pragma unroll
            for (int kk = 0; kk < 4; ++kk) {
                float s = xv[kk];
                const f4* wr = &wlds[(k4 * 4 + kk) * 32 + cg];
#pragma unroll
                for (int q = 0; q < 4; ++q) acc[q] += s * wr[q * 8];
            }
        }
        if (rw < N) {
            __half* d = g16 + (size_t)rw * 256;
#pragma unroll
            for (int q = 0; q < 4; ++q) {
                __half2 h0 = __floats2half2_rn(acc[q][0] * dv, acc[q][1] * dv);
                __half2 h1 = __floats2half2_rn(acc[q][2] * dv, acc[q][3] * dv);
                uint2 pk;
                pk.x = *(uint32_t*)&h0; pk.y = *(uint32_t*)&h1;
                *(uint2*)(d + q * 32 + cg * 4) = pk;
            }
        }
    }
}

// ---- agg phase: one wave per node, lane owns cols {2L,2L+1}; fp32 accumulate ----
__device__ __forceinline__ void agg_phase(const __half2* __restrict__ gh,
                                          const int* __restrict__ csr,
                                          const int* __restrict__ off,
                                          const float* __restrict__ dinv,
                                          const float2* __restrict__ bias2,
                                          float2* __restrict__ out2, int N, int NB) {
    int t = threadIdx.x;
    int lane = t & 63;
    int gw = (blockIdx.x * 1024 + t) >> 6;
    int stride = NB * 16;
    for (int wid = gw; wid < N; wid += stride) {
        float di = dinv[wid];
        float2 self = __half22float2(gh[(size_t)wid * 128 + lane]);
        float a0 = self.x, a1 = self.y;
        int s = off[wid], e = off[wid + 1];
        for (int base = s; base < e; base += 64) {
            int idx = 0;
            if (base + lane < e) idx = csr[base + lane];
            int cnt = e - base; if (cnt > 64) cnt = 64;
            int tt = 0;
            for (; tt + 8 <= cnt; tt += 8) {
                float2 v[8];
#pragma unroll
                for (int u = 0; u < 8; ++u) {
                    int rr = __shfl(idx, tt + u);
                    v[u] = __half22float2(gh[(size_t)rr * 128 + lane]);
                }
#pragma unroll
                for (int u = 0; u < 8; ++u) { a0 += v[u].x; a1 += v[u].y; }
            }
            for (; tt < cnt; ++tt) {
                int rr = __shfl(idx, tt);
                float2 v = __half22float2(gh[(size_t)rr * 128 + lane]);
                a0 += v.x; a1 += v.y;
            }
        }
        float2 bb = bias2[lane];
        float2 o;
        o.x = fmaxf(fmaf(di, a0, bb.x), 0.0f);
        o.y = fmaxf(fmaf(di, a1, bb.y), 0.0f);
        out2[(size_t)wid * 64 + lane] = o;
    }
}

// ---- the persistent mega-kernel ----
__global__ __launch_bounds__(1024, 8) void mega(
    const int* __restrict__ row, const int* __restrict__ col,
    const float* __restrict__ W1, const float2* __restrict__ b1,
    const float* __restrict__ W2, const float2* __restrict__ b2,
    float* __restrict__ xbuf, float* __restrict__ out,
    int* __restrict__ off, float* __restrict__ dinv,
    int* __restrict__ csr, int* __restrict__ gcur,
    uint32_t* __restrict__ binned, int* __restrict__ bar,
    int N, int E, int nbuck, int NB)
{
    __shared__ f4 wlds[4096];   // 64 KB; aliased by bin/bucket scratch
    int t = threadIdx.x;
    __half* g16 = (__half*)xbuf;

    // ---- P1: bin edges into per-bucket regions, packed (row<<8 | node_in_bucket) ----
    {
        int* hist  = (int*)wlds;
        int* hbase = hist + 256;
        int chunks = (E + 4095) >> 12;
        for (int c = blockIdx.x; c < chunks; c += NB) {
            if (t < 256) hist[t] = 0;
            __syncthreads();
            int cc[4]; uint32_t pk[4];
            int e0 = (c << 12) + t;
#pragma unroll
            for (int i = 0; i < 4; ++i) {
                int e = e0 + (i << 10);
                cc[i] = -1; pk[i] = 0;
                if (e < E) {
                    int cv = col[e];
                    if ((unsigned)cv < (unsigned)N) {
                        cc[i] = cv >> BSHIFT;
                        pk[i] = ((uint32_t)row[e] << BSHIFT) | (uint32_t)(cv & BMASK);
                    }
                }
            }
#pragma unroll
            for (int i = 0; i < 4; ++i)
                if (cc[i] >= 0) atomicAdd(&hist[cc[i]], 1);
            __syncthreads();
            if (t < 256) {
                int hh = hist[t];
                if (hh > 0) hbase[t] = atomicAdd(&gcur[t], hh);
                hist[t] = 0;
            }
            __syncthreads();
#pragma unroll
            for (int i = 0; i < 4; ++i)
                if (cc[i] >= 0) {
                    int b = cc[i];
                    int p = hbase[b] + atomicAdd(&hist[b], 1);
                    if (p < BCAP) binned[((size_t)b << 13) + p] = pk[i];
                }
            __syncthreads();
        }
    }
    gridbar(bar, NB * 1);

    // ---- P2: per-bucket -> off / dinv / csr ----
    if (blockIdx.x < nbuck) {
        int b = blockIdx.x;
        int* wtot  = (int*)wlds;
        int* sbase = wtot + 4;
        int* hist  = sbase + 256;
        int* cur   = hist + 256;
        int lane = t & 63, w = t >> 6;
        int v = 0, inc = 0;
        if (t < 256) {
            v = (t < nbuck) ? gcur[t] : 0;
            inc = v;
#pragma unroll
            for (int d = 1; d < 64; d <<= 1) { int u = __shfl_up(inc, d); if (lane >= d) inc += u; }
            if (lane == 63) wtot[w] = inc;
        }
        __syncthreads();
        if (t < 256) {
            int wb = 0;
            for (int i = 0; i < w; ++i) wb += wtot[i];
            sbase[t] = wb + inc - v;
        }
        __syncthreads();
        int base_b = sbase[b];
        int c_b    = gcur[b];
        if (t < 256) hist[t] = 0;
        __syncthreads();
        const uint32_t* reg = binned + ((size_t)b << 13);
        for (int j = t; j < c_b; j += 1024) atomicAdd(&hist[reg[j] & BMASK], 1);
        __syncthreads();
        int h = 0, lo = 0;
        if (t < 256) {
            h = hist[t];
            int inc2 = h;
#pragma unroll
            for (int d = 1; d < 64; d <<= 1) { int u = __shfl_up(inc2, d); if (lane >= d) inc2 += u; }
            if (lane == 63) wtot[w] = inc2;
            lo = inc2 - h;
        }
        __syncthreads();
        if (t < 256) {
            int wb2 = 0;
            for (int i = 0; i < w; ++i) wb2 += wtot[i];
            lo += wb2;
            int node = (b << BSHIFT) + t;
            if (node < N) {
                off[node]  = base_b + lo;
                dinv[node] = rsqrtf((float)(h + 1));   // +1: self-loop
            }
            if (b == nbuck - 1 && t == 0) off[N] = sbase[nbuck - 1] + gcur[nbuck - 1];
            cur[t] = base_b + lo;
        }
        __syncthreads();
        for (int j = t; j < c_b; j += 1024) {
            uint32_t pv = reg[j];
            int p = atomicAdd(&cur[pv & BMASK], 1);
            csr[p] = (int)(pv >> BSHIFT);
        }
    }
    gridbar(bar, NB * 2);

    // ---- P3: layer-1 gemm (in-place xbuf -> fp16 slots) ----
    gemm_phase(wlds, xbuf, W1, dinv, g16, N, NB);
    gridbar(bar, NB * 3);

    // ---- P4: layer-1 aggregation -> act1 (fp32) in `out` ----
    agg_phase((const __half2*)g16, csr, off, dinv, b1, (float2*)out, N, NB);
    gridbar(bar, NB * 4);

    // ---- P5: layer-2 gemm (out -> fp16 slots over xbuf) ----
    gemm_phase(wlds, out, W2, dinv, g16, N, NB);
    gridbar(bar, NB * 5);

    // ---- P6: layer-2 aggregation -> final output ----
    agg_phase((const __half2*)g16, csr, off, dinv, b2, (float2*)out, N, NB);
}

// ---------- launch ----------
extern "C" void kernel_launch(void* const* d_in, const int* in_sizes, int n_in,
                              void* d_out, int out_size, void* d_ws, size_t ws_size,
                              hipStream_t stream) {
    float*       xbuf = (float*)d_in[0];        // fp32 input; reused as slotted fp16 g-table
    const int*   ei   = (const int*)d_in[1];
    const float* W1   = (const float*)d_in[2];
    const float* b1   = (const float*)d_in[3];
    const float* W2   = (const float*)d_in[4];
    const float* b2   = (const float*)d_in[5];
    float*       out  = (float*)d_out;

    int N = in_sizes[0] / 128;
    int E = in_sizes[1] / 2;
    const int* row = ei;          // sources (x_j)
    const int* col = ei + E;      // targets (aggregate index)

    int nbuck = (N + 255) >> BSHIFT;   // 196 for N=50000

    auto align256 = [](size_t v) { return (v + 255) & ~(size_t)255; };
    char* ws = (char*)d_ws;
    size_t pos = 0;
    int*      off    = (int*)(ws + pos);      pos += align256((size_t)(N + 1) * 4);
    float*    dinv   = (float*)(ws + pos);    pos += align256((size_t)N * 4);
    int*      csr    = (int*)(ws + pos);      pos += align256((size_t)E * 4);
    int*      gcur   = (int*)(ws + pos);      pos += align256(320 * 4);   // gcur[256] + bar
    int*      bar    = gcur + 256;
    uint32_t* binned = (uint32_t*)(ws + pos); pos += align256((size_t)nbuck * BCAP * 4);

    // exact co-residency grid (deadlock-safe): blocks/CU from the occupancy API
    int bpc = 0;
    (void)hipOccupancyMaxActiveBlocksPerMultiprocessor(&bpc, mega, 1024, 0);
    if (bpc < 1) bpc = 1;
    int NB = bpc * 256;            // 256 CUs on MI355X
    if (NB > 512) NB = 512;
    if (NB < nbuck) NB = nbuck;    // P2 needs one block per bucket

    hipMemsetAsync(gcur, 0, 320 * 4, stream);   // zero bucket cursors + barrier counter
    mega<<<NB, 1024, 0, stream>>>(row, col, W1, (const float2*)b1, W2, (const float2*)b2,
                                  xbuf, out, off, dinv, csr, gcur, binned, bar,
                                  N, E, nbuck, NB);
}

// Round 13
// 372.296 us; speedup vs baseline: 3.0820x; 3.0820x over previous
//
#include <hip/hip_runtime.h>
#include <hip/hip_fp16.h>
#include <stdint.h>

typedef float f4 __attribute__((ext_vector_type(4)));

#define BSHIFT 8
#define BMASK  255
#define BK     8192   // csr slot stride per 256-node bucket (mean fill 4096)

// ---------- buildcsr: one block per bucket; streams col[], builds off/end/dinv/csr ----------
__global__ __launch_bounds__(1024) void buildcsr(const int* __restrict__ row,
                                                 const int* __restrict__ col,
                                                 int* __restrict__ off,
                                                 int* __restrict__ end,
                                                 float* __restrict__ dinv,
                                                 int* __restrict__ csr,
                                                 int N, int E) {
    __shared__ uint32_t buf[BK];      // 32 KB: packed (row<<8 | node_in_bucket)
    __shared__ int hist[256];
    __shared__ int cur[256];
    __shared__ int wtot[4];
    __shared__ int nsel;
    int t = threadIdx.x;
    int b = blockIdx.x;
    if (t < 256) hist[t] = 0;
    if (t == 0) nsel = 0;
    __syncthreads();

    int nvec = E >> 2;
    const int4* col4 = (const int4*)col;
    for (int i = t; i < nvec; i += 1024) {
        int4 cv = col4[i];
        int e = i << 2;
        int cs[4] = {cv.x, cv.y, cv.z, cv.w};
#pragma unroll
        for (int j = 0; j < 4; ++j) {
            int c = cs[j];
            if ((c >> BSHIFT) == b && (unsigned)c < (unsigned)N) {
                int r = row[e + j];
                int p = atomicAdd(&nsel, 1);
                if (p < BK) buf[p] = ((uint32_t)r << BSHIFT) | (uint32_t)(c & BMASK);
                atomicAdd(&hist[c & BMASK], 1);
            }
        }
    }
    for (int e = (nvec << 2) + t; e < E; e += 1024) {   // tail (E%4)
        int c = col[e];
        if ((c >> BSHIFT) == b && (unsigned)c < (unsigned)N) {
            int r = row[e];
            int p = atomicAdd(&nsel, 1);
            if (p < BK) buf[p] = ((uint32_t)r << BSHIFT) | (uint32_t)(c & BMASK);
            atomicAdd(&hist[c & BMASK], 1);
        }
    }
    __syncthreads();

    int lane = t & 63, w = t >> 6;
    int h = 0, pfx = 0;
    if (t < 256) {
        h = hist[t];
        int inc = h;
#pragma unroll
        for (int d = 1; d < 64; d <<= 1) { int u = __shfl_up(inc, d); if (lane >= d) inc += u; }
        if (lane == 63) wtot[w] = inc;
        pfx = inc - h;
    }
    __syncthreads();
    if (t < 256) {
        int wb = 0;
        for (int i = 0; i < w; ++i) wb += wtot[i];
        pfx += wb;
        int start = b * BK + pfx;
        int node = (b << BSHIFT) + t;
        if (node < N) {
            off[node]  = start;
            end[node]  = start + h;
            dinv[node] = rsqrtf((float)(h + 1));   // +1: self-loop
        }
        cur[t] = start;
    }
    __syncthreads();

    int ns = nsel < BK ? nsel : BK;
    for (int j = t; j < ns; j += 1024) {
        uint32_t pv = buf[j];
        int p = atomicAdd(&cur[pv & BMASK], 1);
        csr[p] = (int)(pv >> BSHIFT);
    }
}

// ---------- gemm (fp32 src): g16[row] = fp16(dinv[row]*(src[row]@W)), 512-B slots ----------
// W staged as fp16 in LDS: wh[k*64 + c/2], k<128, c2<64 -> 8192 half2 = 32 KB.
// (R12 bug: array was declared 4096 -> k>=64 read past LDS -> inf. Fixed.)
__global__ __launch_bounds__(256) void gemm_f32(const float* __restrict__ src,
                                                const float* __restrict__ W,
                                                const float* __restrict__ dinv,
                                                __half* __restrict__ g16, int nrows) {
    __shared__ __half2 wh[8192];   // idx = k*64 + c/2
    int tid = threadIdx.x;
    const float2* w2 = (const float2*)W;
    for (int i = tid; i < 8192; i += 256) {
        float2 v = w2[i];
        wh[i] = __floats2half2_rn(v.x, v.y);
    }
    __syncthreads();

    int r    = tid >> 3;       // 0..31
    int cgrp = tid & 7;        // 0..7
    int row0 = blockIdx.x * 64;
    int ra = row0 + r;
    int rb = row0 + r + 32;
    int raC = ra < nrows ? ra : nrows - 1;
    int rbC = rb < nrows ? rb : nrows - 1;
    const f4* xa4 = (const f4*)(src + (size_t)raC * 128);
    const f4* xb4 = (const f4*)(src + (size_t)rbC * 128);
    float dva = dinv[raC];
    float dvb = dinv[rbC];

    f4 acca[4], accb[4];
#pragma unroll
    for (int q = 0; q < 4; ++q) { acca[q] = (f4)0.0f; accb[q] = (f4)0.0f; }

    for (int k4 = 0; k4 < 32; ++k4) {
        f4 va = xa4[k4];
        f4 vb = xb4[k4];
#pragma unroll
        for (int kk = 0; kk < 4; ++kk) {
            int k = k4 * 4 + kk;
            float sa = va[kk], sb = vb[kk];
            const __half2* wr = &wh[k * 64 + cgrp * 2];
#pragma unroll
            for (int q = 0; q < 4; ++q) {
                float2 fa = __half22float2(wr[q * 16]);
                float2 fb = __half22float2(wr[q * 16 + 1]);
                f4 wv = {fa.x, fa.y, fb.x, fb.y};
                acca[q] += sa * wv;
                accb[q] += sb * wv;
            }
        }
    }

    if (ra < nrows) {
        __half* d = g16 + (size_t)ra * 256;
#pragma unroll
        for (int q = 0; q < 4; ++q) {
            __half2 h0 = __floats2half2_rn(acca[q][0] * dva, acca[q][1] * dva);
            __half2 h1 = __floats2half2_rn(acca[q][2] * dva, acca[q][3] * dva);
            uint2 pk; pk.x = *(uint32_t*)&h0; pk.y = *(uint32_t*)&h1;
            *(uint2*)(d + q * 32 + cgrp * 4) = pk;
        }
    }
    if (rb < nrows) {
        __half* d = g16 + (size_t)rb * 256;
#pragma unroll
        for (int q = 0; q < 4; ++q) {
            __half2 h0 = __floats2half2_rn(accb[q][0] * dvb, accb[q][1] * dvb);
            __half2 h1 = __floats2half2_rn(accb[q][2] * dvb, accb[q][3] * dvb);
            uint2 pk; pk.x = *(uint32_t*)&h0; pk.y = *(uint32_t*)&h1;
            *(uint2*)(d + q * 32 + cgrp * 4) = pk;
        }
    }
}

// ---------- gemm (fp16 src): same, src rows are compact fp16[128] ----------
__global__ __launch_bounds__(256) void gemm_f16(const __half* __restrict__ src,
                                                const float* __restrict__ W,
                                                const float* __restrict__ dinv,
                                                __half* __restrict__ g16, int nrows) {
    __shared__ __half2 wh[8192];
    int tid = threadIdx.x;
    const float2* w2 = (const float2*)W;
    for (int i = tid; i < 8192; i += 256) {
        float2 v = w2[i];
        wh[i] = __floats2half2_rn(v.x, v.y);
    }
    __syncthreads();

    int r    = tid >> 3;
    int cgrp = tid & 7;
    int row0 = blockIdx.x * 64;
    int ra = row0 + r;
    int rb = row0 + r + 32;
    int raC = ra < nrows ? ra : nrows - 1;
    int rbC = rb < nrows ? rb : nrows - 1;
    const uint4* xa = (const uint4*)(src + (size_t)raC * 128);
    const uint4* xb = (const uint4*)(src + (size_t)rbC * 128);
    float dva = dinv[raC];
    float dvb = dinv[rbC];

    f4 acca[4], accb[4];
#pragma unroll
    for (int q = 0; q < 4; ++q) { acca[q] = (f4)0.0f; accb[q] = (f4)0.0f; }

    for (int k8 = 0; k8 < 16; ++k8) {      // 8 k-values per iter (16 B fp16)
        uint4 rawa = xa[k8];
        uint4 rawb = xb[k8];
        uint32_t wa[4] = {rawa.x, rawa.y, rawa.z, rawa.w};
        uint32_t wbv[4] = {rawb.x, rawb.y, rawb.z, rawb.w};
#pragma unroll
        for (int jj = 0; jj < 4; ++jj) {
            float2 fa2 = __half22float2(*(__half2*)&wa[jj]);
            float2 fb2 = __half22float2(*(__half2*)&wbv[jj]);
#pragma unroll
            for (int half_i = 0; half_i < 2; ++half_i) {
                int k = k8 * 8 + jj * 2 + half_i;
                float sa = half_i ? fa2.y : fa2.x;
                float sb = half_i ? fb2.y : fb2.x;
                const __half2* wr = &wh[k * 64 + cgrp * 2];
#pragma unroll
                for (int q = 0; q < 4; ++q) {
                    float2 ga = __half22float2(wr[q * 16]);
                    float2 gb = __half22float2(wr[q * 16 + 1]);
                    f4 wv = {ga.x, ga.y, gb.x, gb.y};
                    acca[q] += sa * wv;
                    accb[q] += sb * wv;
                }
            }
        }
    }

    if (ra < nrows) {
        __half* d = g16 + (size_t)ra * 256;
#pragma unroll
        for (int q = 0; q < 4; ++q) {
            __half2 h0 = __floats2half2_rn(acca[q][0] * dva, acca[q][1] * dva);
            __half2 h1 = __floats2half2_rn(acca[q][2] * dva, acca[q][3] * dva);
            uint2 pk; pk.x = *(uint32_t*)&h0; pk.y = *(uint32_t*)&h1;
            *(uint2*)(d + q * 32 + cgrp * 4) = pk;
        }
    }
    if (rb < nrows) {
        __half* d = g16 + (size_t)rb * 256;
#pragma unroll
        for (int q = 0; q < 4; ++q) {
            __half2 h0 = __floats2half2_rn(accb[q][0] * dvb, accb[q][1] * dvb);
            __half2 h1 = __floats2half2_rn(accb[q][2] * dvb, accb[q][3] * dvb);
            uint2 pk; pk.x = *(uint32_t*)&h0; pk.y = *(uint32_t*)&h1;
            *(uint2*)(d + q * 32 + cgrp * 4) = pk;
        }
    }
}

// ---------- aggregation: one wave per node; writes fp16 act (layer 1) ----------
__global__ __launch_bounds__(256) void agg_h(const __half2* __restrict__ gh,   // slotted
                                             const int* __restrict__ csr,
                                             const int* __restrict__ off,
                                             const int* __restrict__ end,
                                             const float* __restrict__ dinv,
                                             const float2* __restrict__ bias2,
                                             __half2* __restrict__ outh,       // [N*64]
                                             int n) {
    int wid  = (blockIdx.x * 256 + threadIdx.x) >> 6;
    int lane = threadIdx.x & 63;
    if (wid >= n) return;
    float di = dinv[wid];
    float2 self = __half22float2(gh[(size_t)wid * 128 + lane]);
    float a0 = self.x, a1 = self.y;
    int s = off[wid], e = end[wid];
    for (int base = s; base < e; base += 64) {
        int idx = 0;
        if (base + lane < e) idx = csr[base + lane];
        int cnt = e - base; if (cnt > 64) cnt = 64;
        int tt = 0;
        for (; tt + 8 <= cnt; tt += 8) {
            float2 v[8];
#pragma unroll
            for (int u = 0; u < 8; ++u) {
                int rr = __shfl(idx, tt + u);
                v[u] = __half22float2(gh[(size_t)rr * 128 + lane]);
            }
#pragma unroll
            for (int u = 0; u < 8; ++u) { a0 += v[u].x; a1 += v[u].y; }
        }
        for (; tt < cnt; ++tt) {
            int rr = __shfl(idx, tt);
            float2 v = __half22float2(gh[(size_t)rr * 128 + lane]);
            a0 += v.x; a1 += v.y;
        }
    }
    float2 bb = bias2[lane];
    float o0 = fmaxf(fmaf(di, a0, bb.x), 0.0f);
    float o1 = fmaxf(fmaf(di, a1, bb.y), 0.0f);
    outh[(size_t)wid * 64 + lane] = __floats2half2_rn(o0, o1);
}

// ---------- aggregation: writes fp32 final output (layer 2) ----------
__global__ __launch_bounds__(256) void agg_f(const __half2* __restrict__ gh,
                                             const int* __restrict__ csr,
                                             const int* __restrict__ off,
                                             const int* __restrict__ end,
                                             const float* __restrict__ dinv,
                                             const float2* __restrict__ bias2,
                                             float2* __restrict__ out2,
                                             int n) {
    int wid  = (blockIdx.x * 256 + threadIdx.x) >> 6;
    int lane = threadIdx.x & 63;
    if (wid >= n) return;
    float di = dinv[wid];
    float2 self = __half22float2(gh[(size_t)wid * 128 + lane]);
    float a0 = self.x, a1 = self.y;
    int s = off[wid], e = end[wid];
    for (int base = s; base < e; base += 64) {
        int idx = 0;
        if (base + lane < e) idx = csr[base + lane];
        int cnt = e - base; if (cnt > 64) cnt = 64;
        int tt = 0;
        for (; tt + 8 <= cnt; tt += 8) {
            float2 v[8];
#pragma unroll
            for (int u = 0; u < 8; ++u) {
                int rr = __shfl(idx, tt + u);
                v[u] = __half22float2(gh[(size_t)rr * 128 + lane]);
            }
#pragma unroll
            for (int u = 0; u < 8; ++u) { a0 += v[u].x; a1 += v[u].y; }
        }
        for (; tt < cnt; ++tt) {
            int rr = __shfl(idx, tt);
            float2 v = __half22float2(gh[(size_t)rr * 128 + lane]);
            a0 += v.x; a1 += v.y;
        }
    }
    float2 bb = bias2[lane];
    float2 o;
    o.x = fmaxf(fmaf(di, a0, bb.x), 0.0f);
    o.y = fmaxf(fmaf(di, a1, bb.y), 0.0f);
    out2[(size_t)wid * 64 + lane] = o;
}

// ---------- launch: 5 dispatches, no memset ----------
extern "C" void kernel_launch(void* const* d_in, const int* in_sizes, int n_in,
                              void* d_out, int out_size, void* d_ws, size_t ws_size,
                              hipStream_t stream) {
    float*       xbuf = (float*)d_in[0];        // fp32 input; reused as slotted fp16 g-table
    const int*   ei   = (const int*)d_in[1];
    const float* W1   = (const float*)d_in[2];
    const float* b1   = (const float*)d_in[3];
    const float* W2   = (const float*)d_in[4];
    const float* b2   = (const float*)d_in[5];
    float*       out  = (float*)d_out;

    int N = in_sizes[0] / 128;
    int E = in_sizes[1] / 2;
    const int* row = ei;          // sources (x_j)
    const int* col = ei + E;      // targets (aggregate index)

    int nbuck = (N + BMASK) >> BSHIFT;   // 196 for N=50000

    auto align256 = [](size_t v) { return (v + 255) & ~(size_t)255; };
    char* ws = (char*)d_ws;
    size_t pos = 0;
    int*   off  = (int*)(ws + pos);   pos += align256((size_t)N * 4);
    int*   end  = (int*)(ws + pos);   pos += align256((size_t)N * 4);
    float* dinv = (float*)(ws + pos); pos += align256((size_t)N * 4);
    int*   csr  = (int*)(ws + pos);   pos += align256((size_t)nbuck * BK * 4);  // 6.4 MB

    __half* g16   = (__half*)xbuf;    // 512-B slots overlaying the fp32 rows
    __half* act1h = (__half*)out;     // compact fp16 act1 in the output buffer

    int gblocks = (N + 63) / 64;
    int ablocks = (N + 3) / 4;

    buildcsr<<<nbuck, 1024, 0, stream>>>(row, col, off, end, dinv, csr, N, E);
    // layer 1: g1 = fp16(dinv*(x@W1)) in-place slots; act1 = relu(di*Σg+b1) fp16 -> out
    gemm_f32<<<gblocks, 256, 0, stream>>>(xbuf, W1, dinv, g16, N);
    agg_h<<<ablocks, 256, 0, stream>>>((const __half2*)g16, csr, off, end, dinv,
                                       (const float2*)b1, (__half2*)act1h, N);
    // layer 2: g2 = fp16(dinv*(act1@W2)) -> slots; out = relu(di*Σg+b2) fp32 -> out
    gemm_f16<<<gblocks, 256, 0, stream>>>(act1h, W2, dinv, g16, N);
    agg_f<<<ablocks, 256, 0, stream>>>((const __half2*)g16, csr, off, end, dinv,
                                       (const float2*)b2, (float2*)out, N);
}

// Round 14
// 273.487 us; speedup vs baseline: 4.1956x; 1.3613x over previous
//
#include <hip/hip_runtime.h>
#include <hip/hip_fp16.h>
#include <stdint.h>

typedef float f4 __attribute__((ext_vector_type(4)));

#define BSHIFT 8
#define BMASK  255
#define BCAP   8192   // edges per 256-node bucket region (mean 4096)

// ---------- bin: edges -> per-bucket regions, packed (row<<8 | node_in_bucket) ----------
// 4096 edges/block; LDS histogram; one global atomic per (block,bucket) chunk.
__global__ __launch_bounds__(256) void bin_kernel(const int* __restrict__ row,
                                                  const int* __restrict__ col,
                                                  int* __restrict__ gcur,
                                                  uint32_t* __restrict__ binned,
                                                  int E, int n, int nbuck) {
    __shared__ int hist[256];
    __shared__ int base[256];
    int t = threadIdx.x;
    hist[t] = 0;
    __syncthreads();
    int e0 = blockIdx.x * 4096 + t;
    int cc[16]; uint32_t pk[16];
#pragma unroll
    for (int i = 0; i < 16; ++i) {
        int e = e0 + i * 256;
        cc[i] = -1; pk[i] = 0;
        if (e < E) {
            int c = col[e];
            if ((unsigned)c < (unsigned)n) {
                cc[i] = c >> BSHIFT;
                pk[i] = ((uint32_t)row[e] << BSHIFT) | (uint32_t)(c & BMASK);
            }
        }
    }
#pragma unroll
    for (int i = 0; i < 16; ++i)
        if (cc[i] >= 0) atomicAdd(&hist[cc[i]], 1);
    __syncthreads();
    if (t < nbuck) {
        base[t] = atomicAdd(&gcur[t], hist[t]);
        hist[t] = 0;
    }
    __syncthreads();
#pragma unroll
    for (int i = 0; i < 16; ++i)
        if (cc[i] >= 0) {
            int b = cc[i];
            int p = base[b] + atomicAdd(&hist[b], 1);
            if (p < BCAP) binned[(size_t)b * BCAP + p] = pk[i];
        }
}

// ---------- bucket: per 256-node bucket -> off (contiguous) / dinv / csr ----------
__global__ __launch_bounds__(256) void bucket_kernel(const uint32_t* __restrict__ binned,
                                                     const int* __restrict__ gcur,
                                                     int* __restrict__ off,
                                                     float* __restrict__ dinv,
                                                     int* __restrict__ csr,
                                                     int n, int nbuck) {
    __shared__ int wtot[4];
    __shared__ int sbase[256];
    __shared__ int hist[256];
    __shared__ int cur[256];
    int t = threadIdx.x;
    int lane = t & 63, w = t >> 6;
    int b = blockIdx.x;

    // exclusive prefix over the bucket counts (196 ints, L2-hot; every block redoes it)
    int v = (t < nbuck) ? gcur[t] : 0;
    int inc = v;
#pragma unroll
    for (int d = 1; d < 64; d <<= 1) { int u = __shfl_up(inc, d); if (lane >= d) inc += u; }
    if (lane == 63) wtot[w] = inc;
    __syncthreads();
    int wb = 0;
    for (int i = 0; i < w; ++i) wb += wtot[i];
    sbase[t] = wb + inc - v;
    __syncthreads();
    int base_b = sbase[b];
    int c_b    = gcur[b];

    // local degree histogram
    hist[t] = 0;
    __syncthreads();
    const uint32_t* reg = binned + (size_t)b * BCAP;
    for (int j = t; j < c_b; j += 256)
        atomicAdd(&hist[reg[j] & BMASK], 1);
    __syncthreads();
    int h = hist[t];

    // local exclusive scan of degrees
    int inc2 = h;
#pragma unroll
    for (int d = 1; d < 64; d <<= 1) { int u = __shfl_up(inc2, d); if (lane >= d) inc2 += u; }
    __syncthreads();
    if (lane == 63) wtot[w] = inc2;
    __syncthreads();
    int wb2 = 0;
    for (int i = 0; i < w; ++i) wb2 += wtot[i];
    int lo = wb2 + inc2 - h;

    int node = (b << BSHIFT) + t;
    if (node < n) {
        off[node]  = base_b + lo;
        dinv[node] = rsqrtf((float)(h + 1));   // +1: self-loop
    }
    if (b == nbuck - 1 && t == 0)
        off[n] = sbase[nbuck - 1] + gcur[nbuck - 1];

    cur[t] = base_b + lo;
    __syncthreads();
    for (int j = t; j < c_b; j += 256) {
        uint32_t pv = reg[j];
        int p = atomicAdd(&cur[pv & BMASK], 1);
        csr[p] = (int)(pv >> BSHIFT);
    }
}

// ---------- gemm (fp32 src): g16[row] = fp16(dinv[row]*(src[row]@W)), 512-B slots ----------
// W staged as fp16 in LDS: wh[k*64 + c/2] -> 8192 half2 = 32 KB (5 blocks/CU).
__global__ __launch_bounds__(256) void gemm_f32(const float* __restrict__ src,
                                                const float* __restrict__ W,
                                                const float* __restrict__ dinv,
                                                __half* __restrict__ g16, int nrows) {
    __shared__ __half2 wh[8192];
    int tid = threadIdx.x;
    const float2* w2 = (const float2*)W;
    for (int i = tid; i < 8192; i += 256) {
        float2 v = w2[i];
        wh[i] = __floats2half2_rn(v.x, v.y);
    }
    __syncthreads();

    int r    = tid >> 3;       // 0..31
    int cgrp = tid & 7;        // 0..7
    int row0 = blockIdx.x * 64;
    int ra = row0 + r;
    int rb = row0 + r + 32;
    int raC = ra < nrows ? ra : nrows - 1;
    int rbC = rb < nrows ? rb : nrows - 1;
    const f4* xa4 = (const f4*)(src + (size_t)raC * 128);
    const f4* xb4 = (const f4*)(src + (size_t)rbC * 128);
    float dva = dinv[raC];
    float dvb = dinv[rbC];

    f4 acca[4], accb[4];
#pragma unroll
    for (int q = 0; q < 4; ++q) { acca[q] = (f4)0.0f; accb[q] = (f4)0.0f; }

    for (int k4 = 0; k4 < 32; ++k4) {
        f4 va = xa4[k4];
        f4 vb = xb4[k4];
#pragma unroll
        for (int kk = 0; kk < 4; ++kk) {
            int k = k4 * 4 + kk;
            float sa = va[kk], sb = vb[kk];
            const __half2* wr = &wh[k * 64 + cgrp * 2];
#pragma unroll
            for (int q = 0; q < 4; ++q) {
                float2 fa = __half22float2(wr[q * 16]);
                float2 fb = __half22float2(wr[q * 16 + 1]);
                f4 wv = {fa.x, fa.y, fb.x, fb.y};
                acca[q] += sa * wv;
                accb[q] += sb * wv;
            }
        }
    }

    if (ra < nrows) {
        __half* d = g16 + (size_t)ra * 256;
#pragma unroll
        for (int q = 0; q < 4; ++q) {
            __half2 h0 = __floats2half2_rn(acca[q][0] * dva, acca[q][1] * dva);
            __half2 h1 = __floats2half2_rn(acca[q][2] * dva, acca[q][3] * dva);
            uint2 pk; pk.x = *(uint32_t*)&h0; pk.y = *(uint32_t*)&h1;
            *(uint2*)(d + q * 32 + cgrp * 4) = pk;
        }
    }
    if (rb < nrows) {
        __half* d = g16 + (size_t)rb * 256;
#pragma unroll
        for (int q = 0; q < 4; ++q) {
            __half2 h0 = __floats2half2_rn(accb[q][0] * dvb, accb[q][1] * dvb);
            __half2 h1 = __floats2half2_rn(accb[q][2] * dvb, accb[q][3] * dvb);
            uint2 pk; pk.x = *(uint32_t*)&h0; pk.y = *(uint32_t*)&h1;
            *(uint2*)(d + q * 32 + cgrp * 4) = pk;
        }
    }
}

// ---------- gemm (fp16 src): same, src rows are compact fp16[128] ----------
__global__ __launch_bounds__(256) void gemm_f16(const __half* __restrict__ src,
                                                const float* __restrict__ W,
                                                const float* __restrict__ dinv,
                                                __half* __restrict__ g16, int nrows) {
    __shared__ __half2 wh[8192];
    int tid = threadIdx.x;
    const float2* w2 = (const float2*)W;
    for (int i = tid; i < 8192; i += 256) {
        float2 v = w2[i];
        wh[i] = __floats2half2_rn(v.x, v.y);
    }
    __syncthreads();

    int r    = tid >> 3;
    int cgrp = tid & 7;
    int row0 = blockIdx.x * 64;
    int ra = row0 + r;
    int rb = row0 + r + 32;
    int raC = ra < nrows ? ra : nrows - 1;
    int rbC = rb < nrows ? rb : nrows - 1;
    const uint4* xa = (const uint4*)(src + (size_t)raC * 128);
    const uint4* xb = (const uint4*)(src + (size_t)rbC * 128);
    float dva = dinv[raC];
    float dvb = dinv[rbC];

    f4 acca[4], accb[4];
#pragma unroll
    for (int q = 0; q < 4; ++q) { acca[q] = (f4)0.0f; accb[q] = (f4)0.0f; }

    for (int k8 = 0; k8 < 16; ++k8) {
        uint4 rawa = xa[k8];
        uint4 rawb = xb[k8];
        uint32_t wa[4] = {rawa.x, rawa.y, rawa.z, rawa.w};
        uint32_t wbv[4] = {rawb.x, rawb.y, rawb.z, rawb.w};
#pragma unroll
        for (int jj = 0; jj < 4; ++jj) {
            float2 fa2 = __half22float2(*(__half2*)&wa[jj]);
            float2 fb2 = __half22float2(*(__half2*)&wbv[jj]);
#pragma unroll
            for (int half_i = 0; half_i < 2; ++half_i) {
                int k = k8 * 8 + jj * 2 + half_i;
                float sa = half_i ? fa2.y : fa2.x;
                float sb = half_i ? fb2.y : fb2.x;
                const __half2* wr = &wh[k * 64 + cgrp * 2];
#pragma unroll
                for (int q = 0; q < 4; ++q) {
                    float2 ga = __half22float2(wr[q * 16]);
                    float2 gb = __half22float2(wr[q * 16 + 1]);
                    f4 wv = {ga.x, ga.y, gb.x, gb.y};
                    acca[q] += sa * wv;
                    accb[q] += sb * wv;
                }
            }
        }
    }

    if (ra < nrows) {
        __half* d = g16 + (size_t)ra * 256;
#pragma unroll
        for (int q = 0; q < 4; ++q) {
            __half2 h0 = __floats2half2_rn(acca[q][0] * dva, acca[q][1] * dva);
            __half2 h1 = __floats2half2_rn(acca[q][2] * dva, acca[q][3] * dva);
            uint2 pk; pk.x = *(uint32_t*)&h0; pk.y = *(uint32_t*)&h1;
            *(uint2*)(d + q * 32 + cgrp * 4) = pk;
        }
    }
    if (rb < nrows) {
        __half* d = g16 + (size_t)rb * 256;
#pragma unroll
        for (int q = 0; q < 4; ++q) {
            __half2 h0 = __floats2half2_rn(accb[q][0] * dvb, accb[q][1] * dvb);
            __half2 h1 = __floats2half2_rn(accb[q][2] * dvb, accb[q][3] * dvb);
            uint2 pk; pk.x = *(uint32_t*)&h0; pk.y = *(uint32_t*)&h1;
            *(uint2*)(d + q * 32 + cgrp * 4) = pk;
        }
    }
}

// ---------- aggregation: one wave per node; writes fp16 act (layer 1) ----------
__global__ __launch_bounds__(256) void agg_h(const __half2* __restrict__ gh,
                                             const int* __restrict__ csr,
                                             const int* __restrict__ off,
                                             const int* __restrict__ end,   // = off+1 (contiguous CSR)
                                             const float* __restrict__ dinv,
                                             const float2* __restrict__ bias2,
                                             __half2* __restrict__ outh,
                                             int n) {
    int wid  = (blockIdx.x * 256 + threadIdx.x) >> 6;
    int lane = threadIdx.x & 63;
    if (wid >= n) return;
    float di = dinv[wid];
    float2 self = __half22float2(gh[(size_t)wid * 128 + lane]);
    float a0 = self.x, a1 = self.y;
    int s = off[wid], e = end[wid];
    for (int base = s; base < e; base += 64) {
        int idx = 0;
        if (base + lane < e) idx = csr[base + lane];
        int cnt = e - base; if (cnt > 64) cnt = 64;
        int tt = 0;
        for (; tt + 8 <= cnt; tt += 8) {
            float2 v[8];
#pragma unroll
            for (int u = 0; u < 8; ++u) {
                int rr = __shfl(idx, tt + u);
                v[u] = __half22float2(gh[(size_t)rr * 128 + lane]);
            }
#pragma unroll
            for (int u = 0; u < 8; ++u) { a0 += v[u].x; a1 += v[u].y; }
        }
        for (; tt < cnt; ++tt) {
            int rr = __shfl(idx, tt);
            float2 v = __half22float2(gh[(size_t)rr * 128 + lane]);
            a0 += v.x; a1 += v.y;
        }
    }
    float2 bb = bias2[lane];
    float o0 = fmaxf(fmaf(di, a0, bb.x), 0.0f);
    float o1 = fmaxf(fmaf(di, a1, bb.y), 0.0f);
    outh[(size_t)wid * 64 + lane] = __floats2half2_rn(o0, o1);
}

// ---------- aggregation: writes fp32 final output (layer 2) ----------
__global__ __launch_bounds__(256) void agg_f(const __half2* __restrict__ gh,
                                             const int* __restrict__ csr,
                                             const int* __restrict__ off,
                                             const int* __restrict__ end,   // = off+1
                                             const float* __restrict__ dinv,
                                             const float2* __restrict__ bias2,
                                             float2* __restrict__ out2,
                                             int n) {
    int wid  = (blockIdx.x * 256 + threadIdx.x) >> 6;
    int lane = threadIdx.x & 63;
    if (wid >= n) return;
    float di = dinv[wid];
    float2 self = __half22float2(gh[(size_t)wid * 128 + lane]);
    float a0 = self.x, a1 = self.y;
    int s = off[wid], e = end[wid];
    for (int base = s; base < e; base += 64) {
        int idx = 0;
        if (base + lane < e) idx = csr[base + lane];
        int cnt = e - base; if (cnt > 64) cnt = 64;
        int tt = 0;
        for (; tt + 8 <= cnt; tt += 8) {
            float2 v[8];
#pragma unroll
            for (int u = 0; u < 8; ++u) {
                int rr = __shfl(idx, tt + u);
                v[u] = __half22float2(gh[(size_t)rr * 128 + lane]);
            }
#pragma unroll
            for (int u = 0; u < 8; ++u) { a0 += v[u].x; a1 += v[u].y; }
        }
        for (; tt < cnt; ++tt) {
            int rr = __shfl(idx, tt);
            float2 v = __half22float2(gh[(size_t)rr * 128 + lane]);
            a0 += v.x; a1 += v.y;
        }
    }
    float2 bb = bias2[lane];
    float2 o;
    o.x = fmaxf(fmaf(di, a0, bb.x), 0.0f);
    o.y = fmaxf(fmaf(di, a1, bb.y), 0.0f);
    out2[(size_t)wid * 64 + lane] = o;
}

// ---------- launch: 7 dispatches ----------
extern "C" void kernel_launch(void* const* d_in, const int* in_sizes, int n_in,
                              void* d_out, int out_size, void* d_ws, size_t ws_size,
                              hipStream_t stream) {
    float*       xbuf = (float*)d_in[0];        // fp32 input; reused as slotted fp16 g-table
    const int*   ei   = (const int*)d_in[1];
    const float* W1   = (const float*)d_in[2];
    const float* b1   = (const float*)d_in[3];
    const float* W2   = (const float*)d_in[4];
    const float* b2   = (const float*)d_in[5];
    float*       out  = (float*)d_out;

    int N = in_sizes[0] / 128;
    int E = in_sizes[1] / 2;
    const int* row = ei;          // sources (x_j)
    const int* col = ei + E;      // targets (aggregate index)

    int nbuck = (N + BMASK) >> BSHIFT;   // 196 for N=50000

    auto align256 = [](size_t v) { return (v + 255) & ~(size_t)255; };
    char* ws = (char*)d_ws;
    size_t pos = 0;
    int*      off    = (int*)(ws + pos);      pos += align256((size_t)(N + 1) * 4);
    float*    dinv   = (float*)(ws + pos);    pos += align256((size_t)N * 4);
    int*      csr    = (int*)(ws + pos);      pos += align256((size_t)E * 4);
    int*      gcur   = (int*)(ws + pos);      pos += align256(256 * 4);
    uint32_t* binned = (uint32_t*)(ws + pos); pos += align256((size_t)nbuck * BCAP * 4);

    __half* g16   = (__half*)xbuf;    // 512-B slots overlaying the fp32 rows
    __half* act1h = (__half*)out;     // compact fp16 act1 in the output buffer

    int binblocks = (E + 4095) / 4096;
    int gblocks   = (N + 63) / 64;
    int ablocks   = (N + 3) / 4;

    hipMemsetAsync(gcur, 0, 256 * 4, stream);
    bin_kernel<<<binblocks, 256, 0, stream>>>(row, col, gcur, binned, E, N, nbuck);
    bucket_kernel<<<nbuck, 256, 0, stream>>>(binned, gcur, off, dinv, csr, N, nbuck);

    // layer 1: g1 = fp16(dinv*(x@W1)) in-place slots; act1 = relu(di*Σg+b1) fp16 -> out
    gemm_f32<<<gblocks, 256, 0, stream>>>(xbuf, W1, dinv, g16, N);
    agg_h<<<ablocks, 256, 0, stream>>>((const __half2*)g16, csr, off, off + 1, dinv,
                                       (const float2*)b1, (__half2*)act1h, N);
    // layer 2: g2 = fp16(dinv*(act1@W2)) -> slots; out = relu(di*Σg+b2) fp32 -> out
    gemm_f16<<<gblocks, 256, 0, stream>>>(act1h, W2, dinv, g16, N);
    agg_f<<<ablocks, 256, 0, stream>>>((const __half2*)g16, csr, off, off + 1, dinv,
                                       (const float2*)b2, (float2*)out, N);
}